// Round 14
// baseline (836.667 us; speedup 1.0000x reference)
//
#include <hip/hip_runtime.h>
#include <hip/hip_bf16.h>

// ---------------------------------------------------------------------------
// CustomMultiheadAttention on MI355X (gfx950)
//   x = softmax((q Wq^T + bq)(k Wk^T + bk)^T / sqrt(64)) (v Wv^T + bv) Wo^T + bo
// Outputs (concat, fp32): x [4,2048,1024], attn [4,16,2048,2048]
//
// Round-14: SINGLE-PASS attn. 16 q-rows/block; unnormalized P (fp16) lives in
// 64KB LDS. Phase A: QK once (key-split waves, K direct-global with ring-3
// register prefetch), exp once, P->LDS, l accumulated. One barrier (l-reduce).
// Phase B: P from LDS -> scale -> fp32 attn store (write-bound floor) + PV on
// unnormalized P (16x16x16, Vt2 layout, V ring-2 prefetch); O scaled at end.
// ~5 barriers/block vs R13's 64 per equivalent work; QK and exp computed once.
// ---------------------------------------------------------------------------

typedef _Float16 h4 __attribute__((ext_vector_type(4)));
typedef _Float16 h8 __attribute__((ext_vector_type(8)));
typedef float f4 __attribute__((ext_vector_type(4)));

#define EMBED 1024
#define HEADS 16
#define HD 64
#define BB 4
#define SS 2048
#define MROWS (BB * SS) // 8192

#define GLD(src, dst)                                                                  \
  __builtin_amdgcn_global_load_lds((const __attribute__((address_space(1))) void*)(src), \
                                   (__attribute__((address_space(3))) void*)(dst), 16, 0, 0)

__device__ inline float fexp2(float x) {
  float r;
  asm("v_exp_f32 %0, %1" : "=v"(r) : "v"(x));
  return r;
}

// ---------------- fused casts fp32 -> fp16 ----------------
__global__ __launch_bounds__(256) void cast3_f32_f16(const float* __restrict__ a,
                                                     const float* __restrict__ b,
                                                     const float* __restrict__ c,
                                                     _Float16* __restrict__ oa,
                                                     _Float16* __restrict__ ob,
                                                     _Float16* __restrict__ oc, int n) {
  const float* in = blockIdx.y == 0 ? a : blockIdx.y == 1 ? b : c;
  _Float16* out = blockIdx.y == 0 ? oa : blockIdx.y == 1 ? ob : oc;
  int i = (blockIdx.x * 256 + threadIdx.x) * 4;
  if (i < n) {
    float4 v = *reinterpret_cast<const float4*>(in + i);
    h4 o = {(_Float16)v.x, (_Float16)v.y, (_Float16)v.z, (_Float16)v.w};
    *reinterpret_cast<h4*>(out + i) = o;
  }
}

__global__ __launch_bounds__(256) void cast4_f32_f16(const float* __restrict__ a,
                                                     const float* __restrict__ b,
                                                     const float* __restrict__ c,
                                                     const float* __restrict__ d,
                                                     _Float16* __restrict__ oa,
                                                     _Float16* __restrict__ ob,
                                                     _Float16* __restrict__ oc,
                                                     _Float16* __restrict__ od, int n) {
  const float* in = blockIdx.y == 0 ? a : blockIdx.y == 1 ? b : blockIdx.y == 2 ? c : d;
  _Float16* out = blockIdx.y == 0 ? oa : blockIdx.y == 1 ? ob : blockIdx.y == 2 ? oc : od;
  int i = (blockIdx.x * 256 + threadIdx.x) * 4;
  if (i < n) {
    float4 v = *reinterpret_cast<const float4*>(in + i);
    h4 o = {(_Float16)v.x, (_Float16)v.y, (_Float16)v.z, (_Float16)v.w};
    *reinterpret_cast<h4*>(out + i) = o;
  }
}

// ---------------- GEMM core (unchanged) -------------------------------------
template <int OUTF32>
__device__ __forceinline__ void gemm_body(const _Float16* __restrict__ A,
                                          const _Float16* __restrict__ W,
                                          const float* __restrict__ bias,
                                          void* __restrict__ out, char* smem) {
  char* la = smem;
  char* lb = smem + 16384;
  const int t = threadIdx.x;
  const int lane = t & 63;
  const int w = t >> 6;
  const int g = lane >> 4, r16 = lane & 15;
  const int wr = (w >> 1) * 64, wc = (w & 1) * 64;
  const int m0 = blockIdx.x * 128, n0 = blockIdx.y * 128;
  const int p_in_wave = (w << 10) + (lane << 4);

  const char* Ab = (const char*)A;
  const char* Wb = (const char*)W;

  f4 acc[4][4] = {};

  for (int kt = 0; kt < EMBED; kt += 64) {
#pragma unroll
    for (int c = 0; c < 4; c++) {
      int p0 = c * 4096 + p_in_wave;
      int row = p0 >> 7;
      int scol = (p0 & 127) ^ ((row & 7) << 4);
      GLD(Ab + ((size_t)(m0 + row) * EMBED + kt) * 2 + scol, la + c * 4096 + (w << 10));
      GLD(Wb + ((size_t)(n0 + row) * EMBED + kt) * 2 + scol, lb + c * 4096 + (w << 10));
    }
    __syncthreads();
    const int sw = (r16 & 7) << 4;
#pragma unroll
    for (int kk = 0; kk < 2; kk++) {
      h8 af[4], bf[4];
#pragma unroll
      for (int m = 0; m < 4; m++)
        af[m] = *(const h8*)(la + (wr + m * 16 + r16) * 128 + ((kk * 64 + 16 * g) ^ sw));
#pragma unroll
      for (int n = 0; n < 4; n++)
        bf[n] = *(const h8*)(lb + (wc + n * 16 + r16) * 128 + ((kk * 64 + 16 * g) ^ sw));
#pragma unroll
      for (int m = 0; m < 4; m++)
#pragma unroll
        for (int n = 0; n < 4; n++)
          acc[m][n] = __builtin_amdgcn_mfma_f32_16x16x32_f16(af[m], bf[n], acc[m][n], 0, 0, 0);
    }
    __syncthreads();
  }

#pragma unroll
  for (int n = 0; n < 4; n++) {
    int gc = n0 + wc + n * 16 + r16;
    float bv = bias[gc];
#pragma unroll
    for (int m = 0; m < 4; m++) {
#pragma unroll
      for (int r = 0; r < 4; r++) {
        int gr = m0 + wr + m * 16 + 4 * g + r;
        float vv = acc[m][n][r] + bv;
        if (OUTF32)
          reinterpret_cast<float*>(out)[(size_t)gr * EMBED + gc] = vv;
        else
          reinterpret_cast<_Float16*>(out)[(size_t)gr * EMBED + gc] = (_Float16)vv;
      }
    }
  }
}

__global__ __launch_bounds__(256, 2) void gemm_qkv(const _Float16* qh, const _Float16* kh,
                                                   const _Float16* vh, const _Float16* wq,
                                                   const _Float16* wk, const _Float16* wv,
                                                   const float* bq, const float* bk,
                                                   const float* bv, _Float16* Q, _Float16* K,
                                                   _Float16* V) {
  __shared__ char smem[32768];
  const int z = blockIdx.z;
  const _Float16* A = z == 0 ? qh : z == 1 ? kh : vh;
  const _Float16* W = z == 0 ? wq : z == 1 ? wk : wv;
  const float* bias = z == 0 ? bq : z == 1 ? bk : bv;
  _Float16* out = z == 0 ? Q : z == 1 ? K : V;
  gemm_body<0>(A, W, bias, (void*)out, smem);
}

__global__ __launch_bounds__(256, 2) void gemm_out(const _Float16* __restrict__ A,
                                                   const _Float16* __restrict__ W,
                                                   const float* __restrict__ bias,
                                                   float* __restrict__ out) {
  __shared__ char smem[32768];
  gemm_body<1>(A, W, bias, (void*)out, smem);
}

// ---------------- V transpose: [B,S,H*64] -> Vt2[B*H][64][2048] -------------
// Key-permuted within each 32-key chunk: key = hf*16 + 4g + j -> pos =
// g*8 + hf*4 + j. Writes 8B-granule, full-line covering.
__global__ __launch_bounds__(256) void transpose_v(const _Float16* __restrict__ Vp,
                                                   _Float16* __restrict__ Vt) {
  __shared__ _Float16 tile[64][72];
  const int s0 = blockIdx.x * 64;
  const int bh = blockIdx.y;
  const int b = bh >> 4, h = bh & 15;
  const int t = threadIdx.x;
#pragma unroll
  for (int it = 0; it < 2; it++) {
    int c = t + it * 256;
    int r = c >> 3, c8 = (c & 7) * 8;
    *reinterpret_cast<float4*>(&tile[r][c8]) =
        *reinterpret_cast<const float4*>(Vp + ((size_t)b * SS + s0 + r) * EMBED + h * HD + c8);
  }
  __syncthreads();
#pragma unroll
  for (int it = 0; it < 2; it++) {
    int c = t + it * 256;
    int d = c >> 3, s8 = (c & 7) * 8;
    int s32 = s8 & 31;
    int hf = s32 >> 4;
    int g0 = (s32 & 8) ? 2 : 0;
    h4 lo = {tile[s8 + 0][d], tile[s8 + 1][d], tile[s8 + 2][d], tile[s8 + 3][d]};
    h4 hi = {tile[s8 + 4][d], tile[s8 + 5][d], tile[s8 + 6][d], tile[s8 + 7][d]};
    _Float16* base = Vt + ((size_t)bh * HD + d) * SS + s0 + (s8 & ~31);
    *reinterpret_cast<h4*>(base + g0 * 8 + hf * 4) = lo;
    *reinterpret_cast<h4*>(base + (g0 + 1) * 8 + hf * 4) = hi;
  }
}

// ---------------- single-pass fused attention -------------------------------
// Grid: (SS/16, B*H). Block 256 = 4 waves; block owns 16 q-rows; wave w owns
// key-quarter [16w,16w+16) of each 64-key tile.
// Phase A (no barriers): QK swapped 16x16x32, K rows direct-global with
// ring-3 register prefetch; lane holds S[key=w*16+4g+r][q=r16]; exp once;
// P fp16 -> LDS [q=r16][key] (XOR swizzle, same-wave read-back); l partial.
// One barrier: cross-wave l reduce (64 floats at smem+65536).
// Phase B (no barriers): pa = P from LDS (b64), attn = f32(pa)*rinv ->
// nontemporal f4 (full 64B line per 4 g-lanes); PV on unnormalized pa via
// mfma_16x16x16f16 with V direct-global ring-2 (Vt2 permuted layout).
// Epilogue: cross-wave O reduce in (dead) P space, scale by rinv, store fp16.
__global__ __launch_bounds__(256, 2) void attn_fused(const _Float16* __restrict__ Q,
                                                     const _Float16* __restrict__ K,
                                                     const _Float16* __restrict__ Vt,
                                                     float* __restrict__ attn_out,
                                                     _Float16* __restrict__ Oh) {
  __shared__ char smem[65792];  // 64KB P + 256B l-reduce
  const int t = threadIdx.x;
  const int lane = t & 63;
  const int w = t >> 6;
  const int g = lane >> 4, r16 = lane & 15;
  const int q0 = blockIdx.x * 16;
  const int bh = blockIdx.y;
  const int b = bh >> 4, h = bh & 15;

  const float CC = 0.1803368801f;  // (1/sqrt(64)) * log2(e)

  const char* kbase = (const char*)K + ((size_t)b * SS * EMBED + h * HD) * 2;
  const char* vtbase = (const char*)Vt + (size_t)bh * HD * SS * 2;

  // hoist Q fragments (B-operand: col=q=r16, k = kk*32 + 8g + j)
  h8 qf[2];
  {
    const _Float16* qptr = Q + ((size_t)b * SS + q0 + r16) * EMBED + h * HD;
#pragma unroll
    for (int kk = 0; kk < 2; kk++)
      qf[kk] = *reinterpret_cast<const h8*>(qptr + kk * 32 + 8 * g);
  }

  // P LDS address for this lane at key-tile kb (same for write and read)
  const int pbase = r16 * 4096 + w * 32 + 8 * g;
  const int pswz = (r16 & 7) << 4;

  // K row address for this wave/lane: row kb*64 + w*16 + r16, half kk
  const char* krow = kbase + (size_t)(w * 16 + r16) * 2048 + 16 * g;

  // ---- Phase A: QK + exp + P->LDS + l partial (no barriers) ----
  float lpart = 0.0f;
  h8 ka[4][2];
#pragma unroll
  for (int i = 0; i < 3; i++) {
    ka[i][0] = *(const h8*)(krow + (size_t)(i * 64) * 2048);
    ka[i][1] = *(const h8*)(krow + (size_t)(i * 64) * 2048 + 64);
  }
#pragma unroll
  for (int kb = 0; kb < 32; kb++) {
    if (kb + 3 < 32) {
      ka[(kb + 3) & 3][0] = *(const h8*)(krow + (size_t)((kb + 3) * 64) * 2048);
      ka[(kb + 3) & 3][1] = *(const h8*)(krow + (size_t)((kb + 3) * 64) * 2048 + 64);
    }
    f4 sf = {0.f, 0.f, 0.f, 0.f};
    sf = __builtin_amdgcn_mfma_f32_16x16x32_f16(ka[kb & 3][0], qf[0], sf, 0, 0, 0);
    sf = __builtin_amdgcn_mfma_f32_16x16x32_f16(ka[kb & 3][1], qf[1], sf, 0, 0, 0);
    float e0 = fexp2(sf[0] * CC);
    float e1 = fexp2(sf[1] * CC);
    float e2 = fexp2(sf[2] * CC);
    float e3 = fexp2(sf[3] * CC);
    lpart += (e0 + e1) + (e2 + e3);
    h4 pa = {(_Float16)e0, (_Float16)e1, (_Float16)e2, (_Float16)e3};
    *reinterpret_cast<h4*>(smem + ((pbase + kb * 128) ^ pswz)) = pa;
  }

  // ---- l cross-wave reduce ----
  lpart += __shfl_xor(lpart, 16, 64);
  lpart += __shfl_xor(lpart, 32, 64);
  float* lr = (float*)(smem + 65536);
  if (lane < 16) lr[w * 16 + r16] = lpart;
  __syncthreads();
  const float rinv = 1.0f / (lr[r16] + lr[16 + r16] + lr[32 + r16] + lr[48 + r16]);

  // ---- Phase B: attn store + PV (no barriers) ----
  f4 oacc[4] = {};
  float* arow = attn_out + ((size_t)bh * SS + q0 + r16) * SS;
  // V frag: row dt*16+r16, keys w*16+4g+j -> Vt2 byte kb*128+(w>>1)*64+16g+8(w&1)
  const char* vrow = vtbase + (size_t)r16 * 4096 + (w >> 1) * 64 + 16 * g + 8 * (w & 1);

  h4 va[3][4];
#pragma unroll
  for (int i = 0; i < 2; i++) {
#pragma unroll
    for (int dt = 0; dt < 4; dt++)
      va[i][dt] = *(const h4*)(vrow + (size_t)(dt * 16) * 4096 + i * 128);
  }
#pragma unroll
  for (int kb = 0; kb < 32; kb++) {
    if (kb + 2 < 32) {
#pragma unroll
      for (int dt = 0; dt < 4; dt++)
        va[(kb + 2) % 3][dt] = *(const h4*)(vrow + (size_t)(dt * 16) * 4096 + (kb + 2) * 128);
    }
    h4 pa = *reinterpret_cast<const h4*>(smem + ((pbase + kb * 128) ^ pswz));
    float a0 = (float)pa[0] * rinv;
    float a1 = (float)pa[1] * rinv;
    float a2 = (float)pa[2] * rinv;
    float a3 = (float)pa[3] * rinv;
    f4 st = {a0, a1, a2, a3};
    __builtin_nontemporal_store(st, reinterpret_cast<f4*>(arow + kb * 64 + w * 16 + 4 * g));
#pragma unroll
    for (int dt = 0; dt < 4; dt++)
      oacc[dt] = __builtin_amdgcn_mfma_f32_16x16x16f16(pa, va[kb % 3][dt], oacc[dt], 0, 0, 0);
  }

  // ---- O cross-wave reduction in dead P space; scale by rinv; store fp16 ----
  __syncthreads();  // all waves done reading P
  float* ro = (float*)(smem + (w & 1) * 8192);  // two 4KB regions
  if (w < 2) {
#pragma unroll
    for (int dt = 0; dt < 4; dt++)
#pragma unroll
      for (int r = 0; r < 4; r++) ro[(4 * g + r) * 64 + dt * 16 + r16] = oacc[dt][r];
  }
  __syncthreads();
  if (w >= 2) {
#pragma unroll
    for (int dt = 0; dt < 4; dt++)
#pragma unroll
      for (int r = 0; r < 4; r++) ro[(4 * g + r) * 64 + dt * 16 + r16] += oacc[dt][r];
  }
  __syncthreads();
  {
    const float* r0 = (const float*)smem;
    const float* r1 = (const float*)(smem + 8192);
    int q = t >> 4, d0 = (t & 15) * 4;
    float rq = 1.0f / (lr[q] + lr[16 + q] + lr[32 + q] + lr[48 + q]);
    h4 o;
#pragma unroll
    for (int i = 0; i < 4; i++)
      o[i] = (_Float16)((r0[q * 64 + d0 + i] + r1[q * 64 + d0 + i]) * rq);
    *reinterpret_cast<h4*>(Oh + ((size_t)b * SS + q0 + q) * EMBED + h * HD + d0) = o;
  }
}

// ---------------------------------------------------------------------------
extern "C" void kernel_launch(void* const* d_in, const int* in_sizes, int n_in,
                              void* d_out, int out_size, void* d_ws, size_t ws_size,
                              hipStream_t stream) {
  const float* q  = (const float*)d_in[0];
  const float* k  = (const float*)d_in[1];
  const float* v  = (const float*)d_in[2];
  const float* Wq = (const float*)d_in[3];
  const float* bq = (const float*)d_in[4];
  const float* Wk = (const float*)d_in[5];
  const float* bk = (const float*)d_in[6];
  const float* Wv = (const float*)d_in[7];
  const float* bv = (const float*)d_in[8];
  const float* Wo = (const float*)d_in[9];
  const float* bo = (const float*)d_in[10];

  const size_t NW = (size_t)EMBED * EMBED;   // 1,048,576
  const size_t NX = (size_t)MROWS * EMBED;   // 8,388,608

  if (ws_size < (4 * NW + 6 * NX) * sizeof(_Float16)) return;  // loud failure
  _Float16* ws  = (_Float16*)d_ws;
  _Float16* wqh = ws;
  _Float16* wkh = wqh + NW;
  _Float16* wvh = wkh + NW;
  _Float16* woh = wvh + NW;
  _Float16* qh  = woh + NW;
  _Float16* kh  = qh + NX;
  _Float16* vh  = kh + NX;
  _Float16* Qh  = vh + NX;
  _Float16* Kh  = Qh + NX;
  _Float16* Vph = Kh + NX;
  _Float16* Vt2 = qh;   // alias: qh dead after gemm_qkv
  _Float16* OhA = kh;   // alias: kh dead after gemm_qkv

  float* xout = (float*)d_out;
  float* attn = xout + NX;

  cast3_f32_f16<<<dim3((NX / 4 + 255) / 256, 3), dim3(256), 0, stream>>>(q, k, v, qh, kh, vh,
                                                                         (int)NX);
  cast4_f32_f16<<<dim3((NW / 4 + 255) / 256, 4), dim3(256), 0, stream>>>(
      Wq, Wk, Wv, Wo, wqh, wkh, wvh, woh, (int)NW);

  dim3 ggrid(MROWS / 128, EMBED / 128), gblk(256);
  gemm_qkv<<<dim3(MROWS / 128, EMBED / 128, 3), gblk, 0, stream>>>(qh, kh, vh, wqh, wkh, wvh,
                                                                   bq, bk, bv, Qh, Kh, Vph);

  transpose_v<<<dim3(SS / 64, BB * HEADS), dim3(256), 0, stream>>>(Vph, Vt2);

  attn_fused<<<dim3(SS / 16, BB * HEADS), dim3(256), 0, stream>>>(Qh, Kh, Vt2, attn, OhA);

  gemm_out<<<ggrid, gblk, 0, stream>>>(OhA, woh, bo, xout);
}

// Round 15
// 444.409 us; speedup vs baseline: 1.8827x; 1.8827x over previous
//
#include <hip/hip_runtime.h>
#include <hip/hip_bf16.h>

// ---------------------------------------------------------------------------
// CustomMultiheadAttention on MI355X (gfx950)
//   x = softmax((q Wq^T + bq)(k Wk^T + bk)^T / sqrt(64)) (v Wv^T + bv) Wo^T + bo
// Outputs (concat, fp32): x [4,2048,1024], attn [4,16,2048,2048]
//
// Round-15: R13 base (465us, prediction-matched) with BARRIER-FREE K-loops.
// Wave-PRIVATE staging: wave w GLDs its own K key-quarter (16 rows x 128B,
// pre-swizzled source / linear dest / XOR read) and its own V column-slice
// (32B x 64 d-rows from natural-layout Vt). Sync = per-wave counted
// s_waitcnt vmcnt(N) (+sched_barrier) — stores are newer than awaited loads
// so store-acks never block (R13's 64 __syncthreads each drained stores).
// 4 barriers total (l-reduce + O-reduce). Everything else identical to R13.
// ---------------------------------------------------------------------------

typedef _Float16 h4 __attribute__((ext_vector_type(4)));
typedef _Float16 h8 __attribute__((ext_vector_type(8)));
typedef float f4 __attribute__((ext_vector_type(4)));

#define EMBED 1024
#define HEADS 16
#define HD 64
#define BB 4
#define SS 2048
#define MROWS (BB * SS) // 8192

#define GLD(src, dst)                                                                  \
  __builtin_amdgcn_global_load_lds((const __attribute__((address_space(1))) void*)(src), \
                                   (__attribute__((address_space(3))) void*)(dst), 16, 0, 0)

#define WAITV(N)                                                                       \
  {                                                                                    \
    asm volatile("s_waitcnt vmcnt(" #N ")" ::: "memory");                              \
    __builtin_amdgcn_sched_barrier(0);                                                 \
  }

__device__ inline float fexp2(float x) {
  float r;
  asm("v_exp_f32 %0, %1" : "=v"(r) : "v"(x));
  return r;
}

// ---------------- fused casts fp32 -> fp16 ----------------
__global__ __launch_bounds__(256) void cast3_f32_f16(const float* __restrict__ a,
                                                     const float* __restrict__ b,
                                                     const float* __restrict__ c,
                                                     _Float16* __restrict__ oa,
                                                     _Float16* __restrict__ ob,
                                                     _Float16* __restrict__ oc, int n) {
  const float* in = blockIdx.y == 0 ? a : blockIdx.y == 1 ? b : c;
  _Float16* out = blockIdx.y == 0 ? oa : blockIdx.y == 1 ? ob : oc;
  int i = (blockIdx.x * 256 + threadIdx.x) * 4;
  if (i < n) {
    float4 v = *reinterpret_cast<const float4*>(in + i);
    h4 o = {(_Float16)v.x, (_Float16)v.y, (_Float16)v.z, (_Float16)v.w};
    *reinterpret_cast<h4*>(out + i) = o;
  }
}

__global__ __launch_bounds__(256) void cast4_f32_f16(const float* __restrict__ a,
                                                     const float* __restrict__ b,
                                                     const float* __restrict__ c,
                                                     const float* __restrict__ d,
                                                     _Float16* __restrict__ oa,
                                                     _Float16* __restrict__ ob,
                                                     _Float16* __restrict__ oc,
                                                     _Float16* __restrict__ od, int n) {
  const float* in = blockIdx.y == 0 ? a : blockIdx.y == 1 ? b : blockIdx.y == 2 ? c : d;
  _Float16* out = blockIdx.y == 0 ? oa : blockIdx.y == 1 ? ob : blockIdx.y == 2 ? oc : od;
  int i = (blockIdx.x * 256 + threadIdx.x) * 4;
  if (i < n) {
    float4 v = *reinterpret_cast<const float4*>(in + i);
    h4 o = {(_Float16)v.x, (_Float16)v.y, (_Float16)v.z, (_Float16)v.w};
    *reinterpret_cast<h4*>(out + i) = o;
  }
}

// ---------------- GEMM core (unchanged from R13) ----------------------------
template <int OUTF32>
__device__ __forceinline__ void gemm_body(const _Float16* __restrict__ A,
                                          const _Float16* __restrict__ W,
                                          const float* __restrict__ bias,
                                          void* __restrict__ out, char* smem) {
  char* la = smem;
  char* lb = smem + 16384;
  const int t = threadIdx.x;
  const int lane = t & 63;
  const int w = t >> 6;
  const int g = lane >> 4, r16 = lane & 15;
  const int wr = (w >> 1) * 64, wc = (w & 1) * 64;
  const int m0 = blockIdx.x * 128, n0 = blockIdx.y * 128;
  const int p_in_wave = (w << 10) + (lane << 4);

  const char* Ab = (const char*)A;
  const char* Wb = (const char*)W;

  f4 acc[4][4] = {};

  for (int kt = 0; kt < EMBED; kt += 64) {
#pragma unroll
    for (int c = 0; c < 4; c++) {
      int p0 = c * 4096 + p_in_wave;
      int row = p0 >> 7;
      int scol = (p0 & 127) ^ ((row & 7) << 4);
      GLD(Ab + ((size_t)(m0 + row) * EMBED + kt) * 2 + scol, la + c * 4096 + (w << 10));
      GLD(Wb + ((size_t)(n0 + row) * EMBED + kt) * 2 + scol, lb + c * 4096 + (w << 10));
    }
    __syncthreads();
    const int sw = (r16 & 7) << 4;
#pragma unroll
    for (int kk = 0; kk < 2; kk++) {
      h8 af[4], bf[4];
#pragma unroll
      for (int m = 0; m < 4; m++)
        af[m] = *(const h8*)(la + (wr + m * 16 + r16) * 128 + ((kk * 64 + 16 * g) ^ sw));
#pragma unroll
      for (int n = 0; n < 4; n++)
        bf[n] = *(const h8*)(lb + (wc + n * 16 + r16) * 128 + ((kk * 64 + 16 * g) ^ sw));
#pragma unroll
      for (int m = 0; m < 4; m++)
#pragma unroll
        for (int n = 0; n < 4; n++)
          acc[m][n] = __builtin_amdgcn_mfma_f32_16x16x32_f16(af[m], bf[n], acc[m][n], 0, 0, 0);
    }
    __syncthreads();
  }

#pragma unroll
  for (int n = 0; n < 4; n++) {
    int gc = n0 + wc + n * 16 + r16;
    float bv = bias[gc];
#pragma unroll
    for (int m = 0; m < 4; m++) {
#pragma unroll
      for (int r = 0; r < 4; r++) {
        int gr = m0 + wr + m * 16 + 4 * g + r;
        float vv = acc[m][n][r] + bv;
        if (OUTF32)
          reinterpret_cast<float*>(out)[(size_t)gr * EMBED + gc] = vv;
        else
          reinterpret_cast<_Float16*>(out)[(size_t)gr * EMBED + gc] = (_Float16)vv;
      }
    }
  }
}

__global__ __launch_bounds__(256, 2) void gemm_qkv(const _Float16* qh, const _Float16* kh,
                                                   const _Float16* vh, const _Float16* wq,
                                                   const _Float16* wk, const _Float16* wv,
                                                   const float* bq, const float* bk,
                                                   const float* bv, _Float16* Q, _Float16* K,
                                                   _Float16* V) {
  __shared__ char smem[32768];
  const int z = blockIdx.z;
  const _Float16* A = z == 0 ? qh : z == 1 ? kh : vh;
  const _Float16* W = z == 0 ? wq : z == 1 ? wk : wv;
  const float* bias = z == 0 ? bq : z == 1 ? bk : bv;
  _Float16* out = z == 0 ? Q : z == 1 ? K : V;
  gemm_body<0>(A, W, bias, (void*)out, smem);
}

__global__ __launch_bounds__(256, 2) void gemm_out(const _Float16* __restrict__ A,
                                                   const _Float16* __restrict__ W,
                                                   const float* __restrict__ bias,
                                                   float* __restrict__ out) {
  __shared__ char smem[32768];
  gemm_body<1>(A, W, bias, (void*)out, smem);
}

// ---------------- V transpose: [B,S,H*64] -> Vt[B*H][64][2048] (natural) ----
__global__ __launch_bounds__(256) void transpose_v(const _Float16* __restrict__ Vp,
                                                   _Float16* __restrict__ Vt) {
  __shared__ _Float16 tile[64][72];
  const int s0 = blockIdx.x * 64;
  const int bh = blockIdx.y;
  const int b = bh >> 4, h = bh & 15;
  const int t = threadIdx.x;
#pragma unroll
  for (int it = 0; it < 2; it++) {
    int c = t + it * 256;
    int r = c >> 3, c8 = (c & 7) * 8;
    *reinterpret_cast<float4*>(&tile[r][c8]) =
        *reinterpret_cast<const float4*>(Vp + ((size_t)b * SS + s0 + r) * EMBED + h * HD + c8);
  }
  __syncthreads();
#pragma unroll
  for (int it = 0; it < 2; it++) {
    int c = t + it * 256;
    int d = c >> 3, s8 = (c & 7) * 8;
    h4 lo = {tile[s8 + 0][d], tile[s8 + 1][d], tile[s8 + 2][d], tile[s8 + 3][d]};
    h4 hi = {tile[s8 + 4][d], tile[s8 + 5][d], tile[s8 + 6][d], tile[s8 + 7][d]};
    _Float16* dst = Vt + ((size_t)bh * HD + d) * SS + s0 + s8;
    *reinterpret_cast<h4*>(dst) = lo;
    *reinterpret_cast<h4*>(dst + 4) = hi;
  }
}

// ---------------- fused attention — key-split waves, barrier-free loops -----
// Grid: (SS/64, B*H). Block 256 = 4 waves. Wave w owns key-quarter
// [16w,16w+16) of each 64-key tile for ALL 64 q-rows. Wave-PRIVATE staging:
//   K: 16 rows x 128B -> LDS[w][buf] (2KB), source pre-XOR ((row&7)<<4),
//      linear dest, read XOR (r16&7)<<4  (rule-21 involution).
//   V: column slice [d=0..63][32B] of natural Vt -> LDS (2KB); read h4 at
//      d*32 + 8g = keys 16w+4g+j — matches PV A k-map (16x16x16).
// Sync: per-wave counted s_waitcnt vmcnt(N); NO __syncthreads in loops.
// LDS: K 16KB | V 16KB (@16384) | l-reduce 1KB (@32768); O-reduce reuses 0/16384.
__global__ __launch_bounds__(256, 2) void attn_fused(const _Float16* __restrict__ Q,
                                                     const _Float16* __restrict__ K,
                                                     const _Float16* __restrict__ Vt,
                                                     float* __restrict__ attn_out,
                                                     _Float16* __restrict__ Oh) {
  __shared__ char smem[33792];
  const int t = threadIdx.x;
  const int lane = t & 63;
  const int w = t >> 6;
  const int g = lane >> 4, r16 = lane & 15;
  const int qt0 = blockIdx.x;
  const int bh = blockIdx.y;
  const int b = bh >> 4, h = bh & 15;
  const int q0 = qt0 * 64;
  const int sw = (r16 & 7) << 4;

  const float CC = 0.1803368801f;  // (1/sqrt(64)) * log2(e)

  const char* kbase = (const char*)K + ((size_t)b * SS * EMBED + h * HD) * 2;
  const char* vtbase = (const char*)Vt + (size_t)bh * HD * SS * 2;

  // per-lane staging source components (wave-private)
  const int kst_row = lane >> 3;          // c*64+lane: row = (c*64+lane)>>3
  const int kst_piece = lane & 7;
  // K source byte-in-row, pre-swizzled; c adds 8 rows
  // V: flat=c*64+lane: d = flat>>1, piece = flat&1

  char* const kreg = smem + w * 4096;            // 2 bufs x 2KB
  char* const vreg = smem + 16384 + w * 4096;    // 2 bufs x 2KB

#define STAGE_KW(buf, kb)                                                              \
  {                                                                                    \
    _Pragma("unroll") for (int c = 0; c < 2; c++) {                                    \
      int row = c * 8 + kst_row;                                                       \
      int sp = (kst_piece * 16) ^ ((row & 7) << 4);                                    \
      GLD(kbase + (size_t)((kb) * 64 + w * 16 + row) * 2048 + sp,                      \
          kreg + (buf) * 2048 + (c * 64 + lane) * 16);                                 \
    }                                                                                  \
  }
#define STAGE_VW(buf, kb)                                                              \
  {                                                                                    \
    _Pragma("unroll") for (int c = 0; c < 2; c++) {                                    \
      int flat = c * 64 + lane;                                                        \
      GLD(vtbase + (size_t)(flat >> 1) * 4096 + (kb) * 128 + w * 32 + (flat & 1) * 16, \
          vreg + (buf) * 2048 + flat * 16);                                            \
    }                                                                                  \
  }

  // hoist Q fragments for all 4 q-subtiles (B-operand: col=q=r16, k=kk*32+8g+j)
  h8 qf[4][2];
#pragma unroll
  for (int qt = 0; qt < 4; qt++) {
    const _Float16* qptr = Q + ((size_t)b * SS + q0 + qt * 16 + r16) * EMBED + h * HD;
#pragma unroll
    for (int kk = 0; kk < 2; kk++)
      qf[qt][kk] = *reinterpret_cast<const h8*>(qptr + kk * 32 + 8 * g);
  }

  // ---- pass 1: per-wave partial l over this wave's key quarter ----
  float s4[4] = {0.f, 0.f, 0.f, 0.f};
  STAGE_KW(0, 0);
  for (int kb = 0; kb < 32; kb++) {
    const int buf = kb & 1;
    if (kb < 31) {
      STAGE_KW(buf ^ 1, kb + 1);
      WAITV(2);
    } else {
      WAITV(0);
    }
    const char* kp = kreg + buf * 2048 + r16 * 128;
    h8 af0 = *(const h8*)(kp + ((16 * g) ^ sw));
    h8 af1 = *(const h8*)(kp + ((64 + 16 * g) ^ sw));
    __builtin_amdgcn_s_setprio(1);
#pragma unroll
    for (int qt = 0; qt < 4; qt++) {
      f4 sf = {0.f, 0.f, 0.f, 0.f};
      sf = __builtin_amdgcn_mfma_f32_16x16x32_f16(af0, qf[qt][0], sf, 0, 0, 0);
      sf = __builtin_amdgcn_mfma_f32_16x16x32_f16(af1, qf[qt][1], sf, 0, 0, 0);
      __builtin_amdgcn_s_setprio(0);
#pragma unroll
      for (int r = 0; r < 4; r++) s4[qt] += fexp2(sf[r] * CC);
      __builtin_amdgcn_s_setprio(1);
    }
    __builtin_amdgcn_s_setprio(0);
  }
  // reduce over g within wave, then across waves via LDS
#pragma unroll
  for (int qt = 0; qt < 4; qt++) {
    s4[qt] += __shfl_xor(s4[qt], 16, 64);
    s4[qt] += __shfl_xor(s4[qt], 32, 64);
  }
  float* lds_l = (float*)(smem + 32768);  // [4 waves][64 q]
  if (lane < 16) {
#pragma unroll
    for (int qt = 0; qt < 4; qt++) lds_l[w * 64 + qt * 16 + lane] = s4[qt];
  }
  __syncthreads();
  float lgr[4];
#pragma unroll
  for (int qt = 0; qt < 4; qt++) {
    int qi = qt * 16 + r16;
    lgr[qt] = -__log2f(lds_l[qi] + lds_l[64 + qi] + lds_l[128 + qi] + lds_l[192 + qi]);
  }

  // ---- pass 2: recompute, write normalized attn, accumulate PV partials ----
  f4 oacc[4][4] = {};  // [qt][dt]: O[q=qt*16+4g+r][d=dt*16+r16], keys quarter w

  STAGE_KW(0, 0);
  STAGE_VW(0, 0);
  for (int kb = 0; kb < 32; kb++) {
    const int buf = kb & 1;
    if (kb == 0) {
      STAGE_KW(1, 1);
      STAGE_VW(1, 1);
      WAITV(4);
    } else if (kb < 31) {
      STAGE_KW(buf ^ 1, kb + 1);
      STAGE_VW(buf ^ 1, kb + 1);
      WAITV(8);
    } else {
      WAITV(4);
    }
    const char* kp = kreg + buf * 2048 + r16 * 128;
    h8 af0 = *(const h8*)(kp + ((16 * g) ^ sw));
    h8 af1 = *(const h8*)(kp + ((64 + 16 * g) ^ sw));
    h4 pa[4];
    __builtin_amdgcn_s_setprio(1);
#pragma unroll
    for (int qt = 0; qt < 4; qt++) {
      f4 sf = {0.f, 0.f, 0.f, 0.f};
      sf = __builtin_amdgcn_mfma_f32_16x16x32_f16(af0, qf[qt][0], sf, 0, 0, 0);
      sf = __builtin_amdgcn_mfma_f32_16x16x32_f16(af1, qf[qt][1], sf, 0, 0, 0);
      __builtin_amdgcn_s_setprio(0);
      float a0 = fexp2(fmaf(sf[0], CC, lgr[qt]));
      float a1 = fexp2(fmaf(sf[1], CC, lgr[qt]));
      float a2 = fexp2(fmaf(sf[2], CC, lgr[qt]));
      float a3 = fexp2(fmaf(sf[3], CC, lgr[qt]));
      f4 st = {a0, a1, a2, a3};
      __builtin_nontemporal_store(
          st, reinterpret_cast<f4*>(attn_out + ((size_t)bh * SS + q0 + qt * 16 + r16) * SS +
                                    kb * 64 + w * 16 + 4 * g));
      pa[qt] = h4{(_Float16)a0, (_Float16)a1, (_Float16)a2, (_Float16)a3};
      __builtin_amdgcn_s_setprio(1);
    }
    // PV over this wave's 16 keys (16x16x16): vf = V[key 16w+4g+j][d=dt*16+r16]
    const char* vp = vreg + buf * 2048;
#pragma unroll
    for (int dt = 0; dt < 4; dt++) {
      h4 vf = *(const h4*)(vp + (dt * 16 + r16) * 32 + 8 * g);
#pragma unroll
      for (int qt = 0; qt < 4; qt++)
        oacc[qt][dt] = __builtin_amdgcn_mfma_f32_16x16x16f16(pa[qt], vf, oacc[qt][dt], 0, 0, 0);
    }
    __builtin_amdgcn_s_setprio(0);
  }

  // ---- O cross-wave reduction (reuses K/V LDS; waves must all be done) ----
  __syncthreads();
  float* ro = (float*)(smem + (w & 1) * 16384);
  if (w < 2) {
#pragma unroll
    for (int qt = 0; qt < 4; qt++)
#pragma unroll
      for (int dt = 0; dt < 4; dt++)
#pragma unroll
        for (int r = 0; r < 4; r++)
          ro[(qt * 16 + 4 * g + r) * 64 + dt * 16 + r16] = oacc[qt][dt][r];
  }
  __syncthreads();
  if (w >= 2) {
#pragma unroll
    for (int qt = 0; qt < 4; qt++)
#pragma unroll
      for (int dt = 0; dt < 4; dt++)
#pragma unroll
        for (int r = 0; r < 4; r++) {
          int a = (qt * 16 + 4 * g + r) * 64 + dt * 16 + r16;
          ro[a] += oacc[qt][dt][r];
        }
  }
  __syncthreads();
  {
    const float* r0 = (const float*)smem;
    const float* r1 = (const float*)(smem + 16384);
    int q = t >> 2, d0 = (t & 3) * 16;
    _Float16* orow = Oh + ((size_t)b * SS + q0 + q) * EMBED + h * HD + d0;
    h8 o0, o1;
#pragma unroll
    for (int i = 0; i < 8; i++)
      o0[i] = (_Float16)(r0[q * 64 + d0 + i] + r1[q * 64 + d0 + i]);
#pragma unroll
    for (int i = 0; i < 8; i++)
      o1[i] = (_Float16)(r0[q * 64 + d0 + 8 + i] + r1[q * 64 + d0 + 8 + i]);
    *reinterpret_cast<h8*>(orow) = o0;
    *reinterpret_cast<h8*>(orow + 8) = o1;
  }
#undef STAGE_KW
#undef STAGE_VW
}

// ---------------------------------------------------------------------------
extern "C" void kernel_launch(void* const* d_in, const int* in_sizes, int n_in,
                              void* d_out, int out_size, void* d_ws, size_t ws_size,
                              hipStream_t stream) {
  const float* q  = (const float*)d_in[0];
  const float* k  = (const float*)d_in[1];
  const float* v  = (const float*)d_in[2];
  const float* Wq = (const float*)d_in[3];
  const float* bq = (const float*)d_in[4];
  const float* Wk = (const float*)d_in[5];
  const float* bk = (const float*)d_in[6];
  const float* Wv = (const float*)d_in[7];
  const float* bv = (const float*)d_in[8];
  const float* Wo = (const float*)d_in[9];
  const float* bo = (const float*)d_in[10];

  const size_t NW = (size_t)EMBED * EMBED;   // 1,048,576
  const size_t NX = (size_t)MROWS * EMBED;   // 8,388,608

  if (ws_size < (4 * NW + 6 * NX) * sizeof(_Float16)) return;  // loud failure
  _Float16* ws  = (_Float16*)d_ws;
  _Float16* wqh = ws;
  _Float16* wkh = wqh + NW;
  _Float16* wvh = wkh + NW;
  _Float16* woh = wvh + NW;
  _Float16* qh  = woh + NW;
  _Float16* kh  = qh + NX;
  _Float16* vh  = kh + NX;
  _Float16* Qh  = vh + NX;
  _Float16* Kh  = Qh + NX;
  _Float16* Vph = Kh + NX;
  _Float16* Vt2 = qh;   // alias: qh dead after gemm_qkv
  _Float16* OhA = kh;   // alias: kh dead after gemm_qkv

  float* xout = (float*)d_out;
  float* attn = xout + NX;

  cast3_f32_f16<<<dim3((NX / 4 + 255) / 256, 3), dim3(256), 0, stream>>>(q, k, v, qh, kh, vh,
                                                                         (int)NX);
  cast4_f32_f16<<<dim3((NW / 4 + 255) / 256, 4), dim3(256), 0, stream>>>(
      Wq, Wk, Wv, Wo, wqh, wkh, wvh, woh, (int)NW);

  dim3 ggrid(MROWS / 128, EMBED / 128), gblk(256);
  gemm_qkv<<<dim3(MROWS / 128, EMBED / 128, 3), gblk, 0, stream>>>(qh, kh, vh, wqh, wkh, wvh,
                                                                   bq, bk, bv, Qh, Kh, Vph);

  transpose_v<<<dim3(SS / 64, BB * HEADS), dim3(256), 0, stream>>>(Vph, Vt2);

  attn_fused<<<dim3(SS / 64, BB * HEADS), dim3(256), 0, stream>>>(Qh, Kh, Vt2, attn, OhA);

  gemm_out<<<ggrid, gblk, 0, stream>>>(OhA, woh, bo, xout);
}

// Round 17
// 411.379 us; speedup vs baseline: 2.0338x; 1.0803x over previous
//
#include <hip/hip_runtime.h>
#include <hip/hip_bf16.h>

// ---------------------------------------------------------------------------
// CustomMultiheadAttention on MI355X (gfx950)
//   x = softmax((q Wq^T + bq)(k Wk^T + bk)^T / sqrt(64)) (v Wv^T + bv) Wo^T + bo
// Outputs (concat, fp32): x [4,2048,1024], attn [4,16,2048,2048]
//
// Round-17: R15 base with CORRECT vmcnt counts restored (pass2: 4 stores/iter
// -> newer-than-needed = 8 mid-loop / 4 last; R16's 20/16 was a race from
// miscounting stores — vmcnt retires IN ORDER, 8 is minimal-correct).
// Kept from R16: XCD-bijective swizzle (bh's 32 q-blocks share one XCD L2),
// nontemporal fp32 stores in gemm_out.
// ---------------------------------------------------------------------------

typedef _Float16 h4 __attribute__((ext_vector_type(4)));
typedef _Float16 h8 __attribute__((ext_vector_type(8)));
typedef float f4 __attribute__((ext_vector_type(4)));

#define EMBED 1024
#define HEADS 16
#define HD 64
#define BB 4
#define SS 2048
#define MROWS (BB * SS) // 8192

#define GLD(src, dst)                                                                  \
  __builtin_amdgcn_global_load_lds((const __attribute__((address_space(1))) void*)(src), \
                                   (__attribute__((address_space(3))) void*)(dst), 16, 0, 0)

#define WAITV(N)                                                                       \
  {                                                                                    \
    asm volatile("s_waitcnt vmcnt(" #N ")" ::: "memory");                              \
    __builtin_amdgcn_sched_barrier(0);                                                 \
  }

__device__ inline float fexp2(float x) {
  float r;
  asm("v_exp_f32 %0, %1" : "=v"(r) : "v"(x));
  return r;
}

// ---------------- fused casts fp32 -> fp16 ----------------
__global__ __launch_bounds__(256) void cast3_f32_f16(const float* __restrict__ a,
                                                     const float* __restrict__ b,
                                                     const float* __restrict__ c,
                                                     _Float16* __restrict__ oa,
                                                     _Float16* __restrict__ ob,
                                                     _Float16* __restrict__ oc, int n) {
  const float* in = blockIdx.y == 0 ? a : blockIdx.y == 1 ? b : c;
  _Float16* out = blockIdx.y == 0 ? oa : blockIdx.y == 1 ? ob : oc;
  int i = (blockIdx.x * 256 + threadIdx.x) * 4;
  if (i < n) {
    float4 v = *reinterpret_cast<const float4*>(in + i);
    h4 o = {(_Float16)v.x, (_Float16)v.y, (_Float16)v.z, (_Float16)v.w};
    *reinterpret_cast<h4*>(out + i) = o;
  }
}

__global__ __launch_bounds__(256) void cast4_f32_f16(const float* __restrict__ a,
                                                     const float* __restrict__ b,
                                                     const float* __restrict__ c,
                                                     const float* __restrict__ d,
                                                     _Float16* __restrict__ oa,
                                                     _Float16* __restrict__ ob,
                                                     _Float16* __restrict__ oc,
                                                     _Float16* __restrict__ od, int n) {
  const float* in = blockIdx.y == 0 ? a : blockIdx.y == 1 ? b : blockIdx.y == 2 ? c : d;
  _Float16* out = blockIdx.y == 0 ? oa : blockIdx.y == 1 ? ob : blockIdx.y == 2 ? oc : od;
  int i = (blockIdx.x * 256 + threadIdx.x) * 4;
  if (i < n) {
    float4 v = *reinterpret_cast<const float4*>(in + i);
    h4 o = {(_Float16)v.x, (_Float16)v.y, (_Float16)v.z, (_Float16)v.w};
    *reinterpret_cast<h4*>(out + i) = o;
  }
}

// ---------------- GEMM core (MODE1 nontemporal fp32 out) --------------------
template <int OUTF32>
__device__ __forceinline__ void gemm_body(const _Float16* __restrict__ A,
                                          const _Float16* __restrict__ W,
                                          const float* __restrict__ bias,
                                          void* __restrict__ out, char* smem) {
  char* la = smem;
  char* lb = smem + 16384;
  const int t = threadIdx.x;
  const int lane = t & 63;
  const int w = t >> 6;
  const int g = lane >> 4, r16 = lane & 15;
  const int wr = (w >> 1) * 64, wc = (w & 1) * 64;
  const int m0 = blockIdx.x * 128, n0 = blockIdx.y * 128;
  const int p_in_wave = (w << 10) + (lane << 4);

  const char* Ab = (const char*)A;
  const char* Wb = (const char*)W;

  f4 acc[4][4] = {};

  for (int kt = 0; kt < EMBED; kt += 64) {
#pragma unroll
    for (int c = 0; c < 4; c++) {
      int p0 = c * 4096 + p_in_wave;
      int row = p0 >> 7;
      int scol = (p0 & 127) ^ ((row & 7) << 4);
      GLD(Ab + ((size_t)(m0 + row) * EMBED + kt) * 2 + scol, la + c * 4096 + (w << 10));
      GLD(Wb + ((size_t)(n0 + row) * EMBED + kt) * 2 + scol, lb + c * 4096 + (w << 10));
    }
    __syncthreads();
    const int sw = (r16 & 7) << 4;
#pragma unroll
    for (int kk = 0; kk < 2; kk++) {
      h8 af[4], bf[4];
#pragma unroll
      for (int m = 0; m < 4; m++)
        af[m] = *(const h8*)(la + (wr + m * 16 + r16) * 128 + ((kk * 64 + 16 * g) ^ sw));
#pragma unroll
      for (int n = 0; n < 4; n++)
        bf[n] = *(const h8*)(lb + (wc + n * 16 + r16) * 128 + ((kk * 64 + 16 * g) ^ sw));
#pragma unroll
      for (int m = 0; m < 4; m++)
#pragma unroll
        for (int n = 0; n < 4; n++)
          acc[m][n] = __builtin_amdgcn_mfma_f32_16x16x32_f16(af[m], bf[n], acc[m][n], 0, 0, 0);
    }
    __syncthreads();
  }

#pragma unroll
  for (int n = 0; n < 4; n++) {
    int gc = n0 + wc + n * 16 + r16;
    float bv = bias[gc];
#pragma unroll
    for (int m = 0; m < 4; m++) {
#pragma unroll
      for (int r = 0; r < 4; r++) {
        int gr = m0 + wr + m * 16 + 4 * g + r;
        float vv = acc[m][n][r] + bv;
        if (OUTF32)
          __builtin_nontemporal_store(vv, &reinterpret_cast<float*>(out)[(size_t)gr * EMBED + gc]);
        else
          reinterpret_cast<_Float16*>(out)[(size_t)gr * EMBED + gc] = (_Float16)vv;
      }
    }
  }
}

__global__ __launch_bounds__(256, 2) void gemm_qkv(const _Float16* qh, const _Float16* kh,
                                                   const _Float16* vh, const _Float16* wq,
                                                   const _Float16* wk, const _Float16* wv,
                                                   const float* bq, const float* bk,
                                                   const float* bv, _Float16* Q, _Float16* K,
                                                   _Float16* V) {
  __shared__ char smem[32768];
  const int z = blockIdx.z;
  const _Float16* A = z == 0 ? qh : z == 1 ? kh : vh;
  const _Float16* W = z == 0 ? wq : z == 1 ? wk : wv;
  const float* bias = z == 0 ? bq : z == 1 ? bk : bv;
  _Float16* out = z == 0 ? Q : z == 1 ? K : V;
  gemm_body<0>(A, W, bias, (void*)out, smem);
}

__global__ __launch_bounds__(256, 2) void gemm_out(const _Float16* __restrict__ A,
                                                   const _Float16* __restrict__ W,
                                                   const float* __restrict__ bias,
                                                   float* __restrict__ out) {
  __shared__ char smem[32768];
  gemm_body<1>(A, W, bias, (void*)out, smem);
}

// ---------------- V transpose: [B,S,H*64] -> Vt[B*H][64][2048] (natural) ----
__global__ __launch_bounds__(256) void transpose_v(const _Float16* __restrict__ Vp,
                                                   _Float16* __restrict__ Vt) {
  __shared__ _Float16 tile[64][72];
  const int s0 = blockIdx.x * 64;
  const int bh = blockIdx.y;
  const int b = bh >> 4, h = bh & 15;
  const int t = threadIdx.x;
#pragma unroll
  for (int it = 0; it < 2; it++) {
    int c = t + it * 256;
    int r = c >> 3, c8 = (c & 7) * 8;
    *reinterpret_cast<float4*>(&tile[r][c8]) =
        *reinterpret_cast<const float4*>(Vp + ((size_t)b * SS + s0 + r) * EMBED + h * HD + c8);
  }
  __syncthreads();
#pragma unroll
  for (int it = 0; it < 2; it++) {
    int c = t + it * 256;
    int d = c >> 3, s8 = (c & 7) * 8;
    h4 lo = {tile[s8 + 0][d], tile[s8 + 1][d], tile[s8 + 2][d], tile[s8 + 3][d]};
    h4 hi = {tile[s8 + 4][d], tile[s8 + 5][d], tile[s8 + 6][d], tile[s8 + 7][d]};
    _Float16* dst = Vt + ((size_t)bh * HD + d) * SS + s0 + s8;
    *reinterpret_cast<h4*>(dst) = lo;
    *reinterpret_cast<h4*>(dst + 4) = hi;
  }
}

// ---------------- fused attention — key-split waves, barrier-free loops -----
// Grid: (32, 64) decoded via XCD-bijective swizzle: flat = bx + 32*by;
// qt0=(flat>>3)&31, bh=(flat&7)+8*(flat>>8) -> all 32 q-blocks of a bh share
// flat%8 = one XCD (its 512KB K+Vt stay in that L2).
// Wave w owns key-quarter [16w,16w+16) for ALL 64 q-rows; wave-private
// staging; per-wave counted vmcnt with IN-ORDER retirement arithmetic:
// pass1 mid: newer-than-needed = L2(next) -> WAITV(2);
// pass2 kb==0: L4(next) -> WAITV(4); mid: S4(prev)+L4(next) -> WAITV(8);
// last: S4(prev) -> WAITV(4). 4 __syncthreads total.
__global__ __launch_bounds__(256, 2) void attn_fused(const _Float16* __restrict__ Q,
                                                     const _Float16* __restrict__ K,
                                                     const _Float16* __restrict__ Vt,
                                                     float* __restrict__ attn_out,
                                                     _Float16* __restrict__ Oh) {
  __shared__ char smem[33792];
  const int t = threadIdx.x;
  const int lane = t & 63;
  const int w = t >> 6;
  const int g = lane >> 4, r16 = lane & 15;
  const int flat = blockIdx.x + 32 * blockIdx.y;
  const int qt0 = (flat >> 3) & 31;
  const int bh = (flat & 7) + 8 * (flat >> 8);
  const int b = bh >> 4, h = bh & 15;
  const int q0 = qt0 * 64;
  const int sw = (r16 & 7) << 4;

  const float CC = 0.1803368801f;  // (1/sqrt(64)) * log2(e)

  const char* kbase = (const char*)K + ((size_t)b * SS * EMBED + h * HD) * 2;
  const char* vtbase = (const char*)Vt + (size_t)bh * HD * SS * 2;

  const int kst_row = lane >> 3;
  const int kst_piece = lane & 7;

  char* const kreg = smem + w * 4096;            // 2 bufs x 2KB
  char* const vreg = smem + 16384 + w * 4096;    // 2 bufs x 2KB

#define STAGE_KW(buf, kb)                                                              \
  {                                                                                    \
    _Pragma("unroll") for (int c = 0; c < 2; c++) {                                    \
      int row = c * 8 + kst_row;                                                       \
      int sp = (kst_piece * 16) ^ ((row & 7) << 4);                                    \
      GLD(kbase + (size_t)((kb) * 64 + w * 16 + row) * 2048 + sp,                      \
          kreg + (buf) * 2048 + (c * 64 + lane) * 16);                                 \
    }                                                                                  \
  }
#define STAGE_VW(buf, kb)                                                              \
  {                                                                                    \
    _Pragma("unroll") for (int c = 0; c < 2; c++) {                                    \
      int flatv = c * 64 + lane;                                                       \
      GLD(vtbase + (size_t)(flatv >> 1) * 4096 + (kb) * 128 + w * 32 + (flatv & 1) * 16, \
          vreg + (buf) * 2048 + flatv * 16);                                           \
    }                                                                                  \
  }

  // hoist Q fragments for all 4 q-subtiles (B-operand: col=q=r16, k=kk*32+8g+j)
  h8 qf[4][2];
#pragma unroll
  for (int qt = 0; qt < 4; qt++) {
    const _Float16* qptr = Q + ((size_t)b * SS + q0 + qt * 16 + r16) * EMBED + h * HD;
#pragma unroll
    for (int kk = 0; kk < 2; kk++)
      qf[qt][kk] = *reinterpret_cast<const h8*>(qptr + kk * 32 + 8 * g);
  }

  // ---- pass 1: per-wave partial l over this wave's key quarter ----
  float s4[4] = {0.f, 0.f, 0.f, 0.f};
  STAGE_KW(0, 0);
  for (int kb = 0; kb < 32; kb++) {
    const int buf = kb & 1;
    if (kb < 31) {
      STAGE_KW(buf ^ 1, kb + 1);
      WAITV(2);
    } else {
      WAITV(0);
    }
    const char* kp = kreg + buf * 2048 + r16 * 128;
    h8 af0 = *(const h8*)(kp + ((16 * g) ^ sw));
    h8 af1 = *(const h8*)(kp + ((64 + 16 * g) ^ sw));
    __builtin_amdgcn_s_setprio(1);
#pragma unroll
    for (int qt = 0; qt < 4; qt++) {
      f4 sf = {0.f, 0.f, 0.f, 0.f};
      sf = __builtin_amdgcn_mfma_f32_16x16x32_f16(af0, qf[qt][0], sf, 0, 0, 0);
      sf = __builtin_amdgcn_mfma_f32_16x16x32_f16(af1, qf[qt][1], sf, 0, 0, 0);
      __builtin_amdgcn_s_setprio(0);
#pragma unroll
      for (int r = 0; r < 4; r++) s4[qt] += fexp2(sf[r] * CC);
      __builtin_amdgcn_s_setprio(1);
    }
    __builtin_amdgcn_s_setprio(0);
  }
#pragma unroll
  for (int qt = 0; qt < 4; qt++) {
    s4[qt] += __shfl_xor(s4[qt], 16, 64);
    s4[qt] += __shfl_xor(s4[qt], 32, 64);
  }
  float* lds_l = (float*)(smem + 32768);  // [4 waves][64 q]
  if (lane < 16) {
#pragma unroll
    for (int qt = 0; qt < 4; qt++) lds_l[w * 64 + qt * 16 + lane] = s4[qt];
  }
  __syncthreads();
  float lgr[4];
#pragma unroll
  for (int qt = 0; qt < 4; qt++) {
    int qi = qt * 16 + r16;
    lgr[qt] = -__log2f(lds_l[qi] + lds_l[64 + qi] + lds_l[128 + qi] + lds_l[192 + qi]);
  }

  // ---- pass 2: recompute, write normalized attn, accumulate PV partials ----
  f4 oacc[4][4] = {};  // [qt][dt]: O[q=qt*16+4g+r][d=dt*16+r16], keys quarter w

  STAGE_KW(0, 0);
  STAGE_VW(0, 0);
  for (int kb = 0; kb < 32; kb++) {
    const int buf = kb & 1;
    if (kb == 0) {
      STAGE_KW(1, 1);
      STAGE_VW(1, 1);
      WAITV(4);
    } else if (kb < 31) {
      STAGE_KW(buf ^ 1, kb + 1);
      STAGE_VW(buf ^ 1, kb + 1);
      WAITV(8);   // newer than needed L4(kb): S4(kb-1) + L4(kb+1)
    } else {
      WAITV(4);   // newer than needed L4(31): S4(30)
    }
    const char* kp = kreg + buf * 2048 + r16 * 128;
    h8 af0 = *(const h8*)(kp + ((16 * g) ^ sw));
    h8 af1 = *(const h8*)(kp + ((64 + 16 * g) ^ sw));
    h4 pa[4];
    __builtin_amdgcn_s_setprio(1);
#pragma unroll
    for (int qt = 0; qt < 4; qt++) {
      f4 sf = {0.f, 0.f, 0.f, 0.f};
      sf = __builtin_amdgcn_mfma_f32_16x16x32_f16(af0, qf[qt][0], sf, 0, 0, 0);
      sf = __builtin_amdgcn_mfma_f32_16x16x32_f16(af1, qf[qt][1], sf, 0, 0, 0);
      __builtin_amdgcn_s_setprio(0);
      float a0 = fexp2(fmaf(sf[0], CC, lgr[qt]));
      float a1 = fexp2(fmaf(sf[1], CC, lgr[qt]));
      float a2 = fexp2(fmaf(sf[2], CC, lgr[qt]));
      float a3 = fexp2(fmaf(sf[3], CC, lgr[qt]));
      f4 st = {a0, a1, a2, a3};
      __builtin_nontemporal_store(
          st, reinterpret_cast<f4*>(attn_out + ((size_t)bh * SS + q0 + qt * 16 + r16) * SS +
                                    kb * 64 + w * 16 + 4 * g));
      pa[qt] = h4{(_Float16)a0, (_Float16)a1, (_Float16)a2, (_Float16)a3};
      __builtin_amdgcn_s_setprio(1);
    }
    // PV over this wave's 16 keys (16x16x16): vf = V[key 16w+4g+j][d=dt*16+r16]
    const char* vp = vreg + buf * 2048;
#pragma unroll
    for (int dt = 0; dt < 4; dt++) {
      h4 vf = *(const h4*)(vp + (dt * 16 + r16) * 32 + 8 * g);
#pragma unroll
      for (int qt = 0; qt < 4; qt++)
        oacc[qt][dt] = __builtin_amdgcn_mfma_f32_16x16x16f16(pa[qt], vf, oacc[qt][dt], 0, 0, 0);
    }
    __builtin_amdgcn_s_setprio(0);
  }

  // ---- O cross-wave reduction (reuses K/V LDS) ----
  __syncthreads();
  float* ro = (float*)(smem + (w & 1) * 16384);
  if (w < 2) {
#pragma unroll
    for (int qt = 0; qt < 4; qt++)
#pragma unroll
      for (int dt = 0; dt < 4; dt++)
#pragma unroll
        for (int r = 0; r < 4; r++)
          ro[(qt * 16 + 4 * g + r) * 64 + dt * 16 + r16] = oacc[qt][dt][r];
  }
  __syncthreads();
  if (w >= 2) {
#pragma unroll
    for (int qt = 0; qt < 4; qt++)
#pragma unroll
      for (int dt = 0; dt < 4; dt++)
#pragma unroll
        for (int r = 0; r < 4; r++) {
          int a = (qt * 16 + 4 * g + r) * 64 + dt * 16 + r16;
          ro[a] += oacc[qt][dt][r];
        }
  }
  __syncthreads();
  {
    const float* r0 = (const float*)smem;
    const float* r1 = (const float*)(smem + 16384);
    int q = t >> 2, d0 = (t & 3) * 16;
    _Float16* orow = Oh + ((size_t)b * SS + q0 + q) * EMBED + h * HD + d0;
    h8 o0, o1;
#pragma unroll
    for (int i = 0; i < 8; i++)
      o0[i] = (_Float16)(r0[q * 64 + d0 + i] + r1[q * 64 + d0 + i]);
#pragma unroll
    for (int i = 0; i < 8; i++)
      o1[i] = (_Float16)(r0[q * 64 + d0 + 8 + i] + r1[q * 64 + d0 + 8 + i]);
    *reinterpret_cast<h8*>(orow) = o0;
    *reinterpret_cast<h8*>(orow + 8) = o1;
  }
#undef STAGE_KW
#undef STAGE_VW
}

// ---------------------------------------------------------------------------
extern "C" void kernel_launch(void* const* d_in, const int* in_sizes, int n_in,
                              void* d_out, int out_size, void* d_ws, size_t ws_size,
                              hipStream_t stream) {
  const float* q  = (const float*)d_in[0];
  const float* k  = (const float*)d_in[1];
  const float* v  = (const float*)d_in[2];
  const float* Wq = (const float*)d_in[3];
  const float* bq = (const float*)d_in[4];
  const float* Wk = (const float*)d_in[5];
  const float* bk = (const float*)d_in[6];
  const float* Wv = (const float*)d_in[7];
  const float* bv = (const float*)d_in[8];
  const float* Wo = (const float*)d_in[9];
  const float* bo = (const float*)d_in[10];

  const size_t NW = (size_t)EMBED * EMBED;   // 1,048,576
  const size_t NX = (size_t)MROWS * EMBED;   // 8,388,608

  if (ws_size < (4 * NW + 6 * NX) * sizeof(_Float16)) return;  // loud failure
  _Float16* ws  = (_Float16*)d_ws;
  _Float16* wqh = ws;
  _Float16* wkh = wqh + NW;
  _Float16* wvh = wkh + NW;
  _Float16* woh = wvh + NW;
  _Float16* qh  = woh + NW;
  _Float16* kh  = qh + NX;
  _Float16* vh  = kh + NX;
  _Float16* Qh  = vh + NX;
  _Float16* Kh  = Qh + NX;
  _Float16* Vph = Kh + NX;
  _Float16* Vt2 = qh;   // alias: qh dead after gemm_qkv
  _Float16* OhA = kh;   // alias: kh dead after gemm_qkv

  float* xout = (float*)d_out;
  float* attn = xout + NX;

  cast3_f32_f16<<<dim3((NX / 4 + 255) / 256, 3), dim3(256), 0, stream>>>(q, k, v, qh, kh, vh,
                                                                         (int)NX);
  cast4_f32_f16<<<dim3((NW / 4 + 255) / 256, 4), dim3(256), 0, stream>>>(
      Wq, Wk, Wv, Wo, wqh, wkh, wvh, woh, (int)NW);

  dim3 ggrid(MROWS / 128, EMBED / 128), gblk(256);
  gemm_qkv<<<dim3(MROWS / 128, EMBED / 128, 3), gblk, 0, stream>>>(qh, kh, vh, wqh, wkh, wvh,
                                                                   bq, bk, bv, Qh, Kh, Vph);

  transpose_v<<<dim3(SS / 64, BB * HEADS), dim3(256), 0, stream>>>(Vph, Vt2);

  attn_fused<<<dim3(SS / 64, BB * HEADS), dim3(256), 0, stream>>>(Qh, Kh, Vt2, attn, OhA);

  gemm_out<<<ggrid, gblk, 0, stream>>>(OhA, woh, bo, xout);
}

// Round 18
// 410.502 us; speedup vs baseline: 2.0382x; 1.0021x over previous
//
#include <hip/hip_runtime.h>
#include <hip/hip_bf16.h>

// ---------------------------------------------------------------------------
// CustomMultiheadAttention on MI355X (gfx950)
//   x = softmax((q Wq^T + bq)(k Wk^T + bk)^T / sqrt(64)) (v Wv^T + bv) Wo^T + bo
// Outputs (concat, fp32): x [4,2048,1024], attn [4,16,2048,2048]
//
// Round-18: R17 (411us) with occupancy raised 2->3 blocks/CU on attn and the
// GEMMs via __launch_bounds__(256,3) — register arithmetic: attn ~150 VGPR,
// gemm ~120 VGPR, both <=170 (3-waves/EU cap); LDS 33.8/32KB <= 160/3.
// +50% TLP to saturate attn store BW and hide GLD latency. No other changes.
// ---------------------------------------------------------------------------

typedef _Float16 h4 __attribute__((ext_vector_type(4)));
typedef _Float16 h8 __attribute__((ext_vector_type(8)));
typedef float f4 __attribute__((ext_vector_type(4)));

#define EMBED 1024
#define HEADS 16
#define HD 64
#define BB 4
#define SS 2048
#define MROWS (BB * SS) // 8192

#define GLD(src, dst)                                                                  \
  __builtin_amdgcn_global_load_lds((const __attribute__((address_space(1))) void*)(src), \
                                   (__attribute__((address_space(3))) void*)(dst), 16, 0, 0)

#define WAITV(N)                                                                       \
  {                                                                                    \
    asm volatile("s_waitcnt vmcnt(" #N ")" ::: "memory");                              \
    __builtin_amdgcn_sched_barrier(0);                                                 \
  }

__device__ inline float fexp2(float x) {
  float r;
  asm("v_exp_f32 %0, %1" : "=v"(r) : "v"(x));
  return r;
}

// ---------------- fused casts fp32 -> fp16 ----------------
__global__ __launch_bounds__(256) void cast3_f32_f16(const float* __restrict__ a,
                                                     const float* __restrict__ b,
                                                     const float* __restrict__ c,
                                                     _Float16* __restrict__ oa,
                                                     _Float16* __restrict__ ob,
                                                     _Float16* __restrict__ oc, int n) {
  const float* in = blockIdx.y == 0 ? a : blockIdx.y == 1 ? b : c;
  _Float16* out = blockIdx.y == 0 ? oa : blockIdx.y == 1 ? ob : oc;
  int i = (blockIdx.x * 256 + threadIdx.x) * 4;
  if (i < n) {
    float4 v = *reinterpret_cast<const float4*>(in + i);
    h4 o = {(_Float16)v.x, (_Float16)v.y, (_Float16)v.z, (_Float16)v.w};
    *reinterpret_cast<h4*>(out + i) = o;
  }
}

__global__ __launch_bounds__(256) void cast4_f32_f16(const float* __restrict__ a,
                                                     const float* __restrict__ b,
                                                     const float* __restrict__ c,
                                                     const float* __restrict__ d,
                                                     _Float16* __restrict__ oa,
                                                     _Float16* __restrict__ ob,
                                                     _Float16* __restrict__ oc,
                                                     _Float16* __restrict__ od, int n) {
  const float* in = blockIdx.y == 0 ? a : blockIdx.y == 1 ? b : blockIdx.y == 2 ? c : d;
  _Float16* out = blockIdx.y == 0 ? oa : blockIdx.y == 1 ? ob : blockIdx.y == 2 ? oc : od;
  int i = (blockIdx.x * 256 + threadIdx.x) * 4;
  if (i < n) {
    float4 v = *reinterpret_cast<const float4*>(in + i);
    h4 o = {(_Float16)v.x, (_Float16)v.y, (_Float16)v.z, (_Float16)v.w};
    *reinterpret_cast<h4*>(out + i) = o;
  }
}

// ---------------- GEMM core (MODE1 nontemporal fp32 out) --------------------
template <int OUTF32>
__device__ __forceinline__ void gemm_body(const _Float16* __restrict__ A,
                                          const _Float16* __restrict__ W,
                                          const float* __restrict__ bias,
                                          void* __restrict__ out, char* smem) {
  char* la = smem;
  char* lb = smem + 16384;
  const int t = threadIdx.x;
  const int lane = t & 63;
  const int w = t >> 6;
  const int g = lane >> 4, r16 = lane & 15;
  const int wr = (w >> 1) * 64, wc = (w & 1) * 64;
  const int m0 = blockIdx.x * 128, n0 = blockIdx.y * 128;
  const int p_in_wave = (w << 10) + (lane << 4);

  const char* Ab = (const char*)A;
  const char* Wb = (const char*)W;

  f4 acc[4][4] = {};

  for (int kt = 0; kt < EMBED; kt += 64) {
#pragma unroll
    for (int c = 0; c < 4; c++) {
      int p0 = c * 4096 + p_in_wave;
      int row = p0 >> 7;
      int scol = (p0 & 127) ^ ((row & 7) << 4);
      GLD(Ab + ((size_t)(m0 + row) * EMBED + kt) * 2 + scol, la + c * 4096 + (w << 10));
      GLD(Wb + ((size_t)(n0 + row) * EMBED + kt) * 2 + scol, lb + c * 4096 + (w << 10));
    }
    __syncthreads();
    const int sw = (r16 & 7) << 4;
#pragma unroll
    for (int kk = 0; kk < 2; kk++) {
      h8 af[4], bf[4];
#pragma unroll
      for (int m = 0; m < 4; m++)
        af[m] = *(const h8*)(la + (wr + m * 16 + r16) * 128 + ((kk * 64 + 16 * g) ^ sw));
#pragma unroll
      for (int n = 0; n < 4; n++)
        bf[n] = *(const h8*)(lb + (wc + n * 16 + r16) * 128 + ((kk * 64 + 16 * g) ^ sw));
#pragma unroll
      for (int m = 0; m < 4; m++)
#pragma unroll
        for (int n = 0; n < 4; n++)
          acc[m][n] = __builtin_amdgcn_mfma_f32_16x16x32_f16(af[m], bf[n], acc[m][n], 0, 0, 0);
    }
    __syncthreads();
  }

#pragma unroll
  for (int n = 0; n < 4; n++) {
    int gc = n0 + wc + n * 16 + r16;
    float bv = bias[gc];
#pragma unroll
    for (int m = 0; m < 4; m++) {
#pragma unroll
      for (int r = 0; r < 4; r++) {
        int gr = m0 + wr + m * 16 + 4 * g + r;
        float vv = acc[m][n][r] + bv;
        if (OUTF32)
          __builtin_nontemporal_store(vv, &reinterpret_cast<float*>(out)[(size_t)gr * EMBED + gc]);
        else
          reinterpret_cast<_Float16*>(out)[(size_t)gr * EMBED + gc] = (_Float16)vv;
      }
    }
  }
}

__global__ __launch_bounds__(256, 3) void gemm_qkv(const _Float16* qh, const _Float16* kh,
                                                   const _Float16* vh, const _Float16* wq,
                                                   const _Float16* wk, const _Float16* wv,
                                                   const float* bq, const float* bk,
                                                   const float* bv, _Float16* Q, _Float16* K,
                                                   _Float16* V) {
  __shared__ char smem[32768];
  const int z = blockIdx.z;
  const _Float16* A = z == 0 ? qh : z == 1 ? kh : vh;
  const _Float16* W = z == 0 ? wq : z == 1 ? wk : wv;
  const float* bias = z == 0 ? bq : z == 1 ? bk : bv;
  _Float16* out = z == 0 ? Q : z == 1 ? K : V;
  gemm_body<0>(A, W, bias, (void*)out, smem);
}

__global__ __launch_bounds__(256, 3) void gemm_out(const _Float16* __restrict__ A,
                                                   const _Float16* __restrict__ W,
                                                   const float* __restrict__ bias,
                                                   float* __restrict__ out) {
  __shared__ char smem[32768];
  gemm_body<1>(A, W, bias, (void*)out, smem);
}

// ---------------- V transpose: [B,S,H*64] -> Vt[B*H][64][2048] (natural) ----
__global__ __launch_bounds__(256) void transpose_v(const _Float16* __restrict__ Vp,
                                                   _Float16* __restrict__ Vt) {
  __shared__ _Float16 tile[64][72];
  const int s0 = blockIdx.x * 64;
  const int bh = blockIdx.y;
  const int b = bh >> 4, h = bh & 15;
  const int t = threadIdx.x;
#pragma unroll
  for (int it = 0; it < 2; it++) {
    int c = t + it * 256;
    int r = c >> 3, c8 = (c & 7) * 8;
    *reinterpret_cast<float4*>(&tile[r][c8]) =
        *reinterpret_cast<const float4*>(Vp + ((size_t)b * SS + s0 + r) * EMBED + h * HD + c8);
  }
  __syncthreads();
#pragma unroll
  for (int it = 0; it < 2; it++) {
    int c = t + it * 256;
    int d = c >> 3, s8 = (c & 7) * 8;
    h4 lo = {tile[s8 + 0][d], tile[s8 + 1][d], tile[s8 + 2][d], tile[s8 + 3][d]};
    h4 hi = {tile[s8 + 4][d], tile[s8 + 5][d], tile[s8 + 6][d], tile[s8 + 7][d]};
    _Float16* dst = Vt + ((size_t)bh * HD + d) * SS + s0 + s8;
    *reinterpret_cast<h4*>(dst) = lo;
    *reinterpret_cast<h4*>(dst + 4) = hi;
  }
}

// ---------------- fused attention — key-split waves, barrier-free loops -----
// Grid: (32, 64) decoded via XCD-bijective swizzle: flat = bx + 32*by;
// qt0=(flat>>3)&31, bh=(flat&7)+8*(flat>>8) -> all 32 q-blocks of a bh share
// flat%8 = one XCD (its 512KB K+Vt stay in that L2).
// Wave w owns key-quarter [16w,16w+16) for ALL 64 q-rows; wave-private
// staging; per-wave counted vmcnt (in-order retirement):
// pass1 mid WAITV(2); pass2 kb==0 WAITV(4), mid WAITV(8) = S4(prev)+L4(next),
// last WAITV(4). 4 __syncthreads total. 3 blocks/CU.
__global__ __launch_bounds__(256, 3) void attn_fused(const _Float16* __restrict__ Q,
                                                     const _Float16* __restrict__ K,
                                                     const _Float16* __restrict__ Vt,
                                                     float* __restrict__ attn_out,
                                                     _Float16* __restrict__ Oh) {
  __shared__ char smem[33792];
  const int t = threadIdx.x;
  const int lane = t & 63;
  const int w = t >> 6;
  const int g = lane >> 4, r16 = lane & 15;
  const int flat = blockIdx.x + 32 * blockIdx.y;
  const int qt0 = (flat >> 3) & 31;
  const int bh = (flat & 7) + 8 * (flat >> 8);
  const int b = bh >> 4, h = bh & 15;
  const int q0 = qt0 * 64;
  const int sw = (r16 & 7) << 4;

  const float CC = 0.1803368801f;  // (1/sqrt(64)) * log2(e)

  const char* kbase = (const char*)K + ((size_t)b * SS * EMBED + h * HD) * 2;
  const char* vtbase = (const char*)Vt + (size_t)bh * HD * SS * 2;

  const int kst_row = lane >> 3;
  const int kst_piece = lane & 7;

  char* const kreg = smem + w * 4096;            // 2 bufs x 2KB
  char* const vreg = smem + 16384 + w * 4096;    // 2 bufs x 2KB

#define STAGE_KW(buf, kb)                                                              \
  {                                                                                    \
    _Pragma("unroll") for (int c = 0; c < 2; c++) {                                    \
      int row = c * 8 + kst_row;                                                       \
      int sp = (kst_piece * 16) ^ ((row & 7) << 4);                                    \
      GLD(kbase + (size_t)((kb) * 64 + w * 16 + row) * 2048 + sp,                      \
          kreg + (buf) * 2048 + (c * 64 + lane) * 16);                                 \
    }                                                                                  \
  }
#define STAGE_VW(buf, kb)                                                              \
  {                                                                                    \
    _Pragma("unroll") for (int c = 0; c < 2; c++) {                                    \
      int flatv = c * 64 + lane;                                                       \
      GLD(vtbase + (size_t)(flatv >> 1) * 4096 + (kb) * 128 + w * 32 + (flatv & 1) * 16, \
          vreg + (buf) * 2048 + flatv * 16);                                           \
    }                                                                                  \
  }

  // hoist Q fragments for all 4 q-subtiles (B-operand: col=q=r16, k=kk*32+8g+j)
  h8 qf[4][2];
#pragma unroll
  for (int qt = 0; qt < 4; qt++) {
    const _Float16* qptr = Q + ((size_t)b * SS + q0 + qt * 16 + r16) * EMBED + h * HD;
#pragma unroll
    for (int kk = 0; kk < 2; kk++)
      qf[qt][kk] = *reinterpret_cast<const h8*>(qptr + kk * 32 + 8 * g);
  }

  // ---- pass 1: per-wave partial l over this wave's key quarter ----
  float s4[4] = {0.f, 0.f, 0.f, 0.f};
  STAGE_KW(0, 0);
  for (int kb = 0; kb < 32; kb++) {
    const int buf = kb & 1;
    if (kb < 31) {
      STAGE_KW(buf ^ 1, kb + 1);
      WAITV(2);
    } else {
      WAITV(0);
    }
    const char* kp = kreg + buf * 2048 + r16 * 128;
    h8 af0 = *(const h8*)(kp + ((16 * g) ^ sw));
    h8 af1 = *(const h8*)(kp + ((64 + 16 * g) ^ sw));
    __builtin_amdgcn_s_setprio(1);
#pragma unroll
    for (int qt = 0; qt < 4; qt++) {
      f4 sf = {0.f, 0.f, 0.f, 0.f};
      sf = __builtin_amdgcn_mfma_f32_16x16x32_f16(af0, qf[qt][0], sf, 0, 0, 0);
      sf = __builtin_amdgcn_mfma_f32_16x16x32_f16(af1, qf[qt][1], sf, 0, 0, 0);
      __builtin_amdgcn_s_setprio(0);
#pragma unroll
      for (int r = 0; r < 4; r++) s4[qt] += fexp2(sf[r] * CC);
      __builtin_amdgcn_s_setprio(1);
    }
    __builtin_amdgcn_s_setprio(0);
  }
#pragma unroll
  for (int qt = 0; qt < 4; qt++) {
    s4[qt] += __shfl_xor(s4[qt], 16, 64);
    s4[qt] += __shfl_xor(s4[qt], 32, 64);
  }
  float* lds_l = (float*)(smem + 32768);  // [4 waves][64 q]
  if (lane < 16) {
#pragma unroll
    for (int qt = 0; qt < 4; qt++) lds_l[w * 64 + qt * 16 + lane] = s4[qt];
  }
  __syncthreads();
  float lgr[4];
#pragma unroll
  for (int qt = 0; qt < 4; qt++) {
    int qi = qt * 16 + r16;
    lgr[qt] = -__log2f(lds_l[qi] + lds_l[64 + qi] + lds_l[128 + qi] + lds_l[192 + qi]);
  }

  // ---- pass 2: recompute, write normalized attn, accumulate PV partials ----
  f4 oacc[4][4] = {};  // [qt][dt]: O[q=qt*16+4g+r][d=dt*16+r16], keys quarter w

  STAGE_KW(0, 0);
  STAGE_VW(0, 0);
  for (int kb = 0; kb < 32; kb++) {
    const int buf = kb & 1;
    if (kb == 0) {
      STAGE_KW(1, 1);
      STAGE_VW(1, 1);
      WAITV(4);
    } else if (kb < 31) {
      STAGE_KW(buf ^ 1, kb + 1);
      STAGE_VW(buf ^ 1, kb + 1);
      WAITV(8);   // newer than needed L4(kb): S4(kb-1) + L4(kb+1)
    } else {
      WAITV(4);   // newer than needed L4(31): S4(30)
    }
    const char* kp = kreg + buf * 2048 + r16 * 128;
    h8 af0 = *(const h8*)(kp + ((16 * g) ^ sw));
    h8 af1 = *(const h8*)(kp + ((64 + 16 * g) ^ sw));
    h4 pa[4];
    __builtin_amdgcn_s_setprio(1);
#pragma unroll
    for (int qt = 0; qt < 4; qt++) {
      f4 sf = {0.f, 0.f, 0.f, 0.f};
      sf = __builtin_amdgcn_mfma_f32_16x16x32_f16(af0, qf[qt][0], sf, 0, 0, 0);
      sf = __builtin_amdgcn_mfma_f32_16x16x32_f16(af1, qf[qt][1], sf, 0, 0, 0);
      __builtin_amdgcn_s_setprio(0);
      float a0 = fexp2(fmaf(sf[0], CC, lgr[qt]));
      float a1 = fexp2(fmaf(sf[1], CC, lgr[qt]));
      float a2 = fexp2(fmaf(sf[2], CC, lgr[qt]));
      float a3 = fexp2(fmaf(sf[3], CC, lgr[qt]));
      f4 st = {a0, a1, a2, a3};
      __builtin_nontemporal_store(
          st, reinterpret_cast<f4*>(attn_out + ((size_t)bh * SS + q0 + qt * 16 + r16) * SS +
                                    kb * 64 + w * 16 + 4 * g));
      pa[qt] = h4{(_Float16)a0, (_Float16)a1, (_Float16)a2, (_Float16)a3};
      __builtin_amdgcn_s_setprio(1);
    }
    // PV over this wave's 16 keys (16x16x16): vf = V[key 16w+4g+j][d=dt*16+r16]
    const char* vp = vreg + buf * 2048;
#pragma unroll
    for (int dt = 0; dt < 4; dt++) {
      h4 vf = *(const h4*)(vp + (dt * 16 + r16) * 32 + 8 * g);
#pragma unroll
      for (int qt = 0; qt < 4; qt++)
        oacc[qt][dt] = __builtin_amdgcn_mfma_f32_16x16x16f16(pa[qt], vf, oacc[qt][dt], 0, 0, 0);
    }
    __builtin_amdgcn_s_setprio(0);
  }

  // ---- O cross-wave reduction (reuses K/V LDS) ----
  __syncthreads();
  float* ro = (float*)(smem + (w & 1) * 16384);
  if (w < 2) {
#pragma unroll
    for (int qt = 0; qt < 4; qt++)
#pragma unroll
      for (int dt = 0; dt < 4; dt++)
#pragma unroll
        for (int r = 0; r < 4; r++)
          ro[(qt * 16 + 4 * g + r) * 64 + dt * 16 + r16] = oacc[qt][dt][r];
  }
  __syncthreads();
  if (w >= 2) {
#pragma unroll
    for (int qt = 0; qt < 4; qt++)
#pragma unroll
      for (int dt = 0; dt < 4; dt++)
#pragma unroll
        for (int r = 0; r < 4; r++) {
          int a = (qt * 16 + 4 * g + r) * 64 + dt * 16 + r16;
          ro[a] += oacc[qt][dt][r];
        }
  }
  __syncthreads();
  {
    const float* r0 = (const float*)smem;
    const float* r1 = (const float*)(smem + 16384);
    int q = t >> 2, d0 = (t & 3) * 16;
    _Float16* orow = Oh + ((size_t)b * SS + q0 + q) * EMBED + h * HD + d0;
    h8 o0, o1;
#pragma unroll
    for (int i = 0; i < 8; i++)
      o0[i] = (_Float16)(r0[q * 64 + d0 + i] + r1[q * 64 + d0 + i]);
#pragma unroll
    for (int i = 0; i < 8; i++)
      o1[i] = (_Float16)(r0[q * 64 + d0 + 8 + i] + r1[q * 64 + d0 + 8 + i]);
    *reinterpret_cast<h8*>(orow) = o0;
    *reinterpret_cast<h8*>(orow + 8) = o1;
  }
#undef STAGE_KW
#undef STAGE_VW
}

// ---------------------------------------------------------------------------
extern "C" void kernel_launch(void* const* d_in, const int* in_sizes, int n_in,
                              void* d_out, int out_size, void* d_ws, size_t ws_size,
                              hipStream_t stream) {
  const float* q  = (const float*)d_in[0];
  const float* k  = (const float*)d_in[1];
  const float* v  = (const float*)d_in[2];
  const float* Wq = (const float*)d_in[3];
  const float* bq = (const float*)d_in[4];
  const float* Wk = (const float*)d_in[5];
  const float* bk = (const float*)d_in[6];
  const float* Wv = (const float*)d_in[7];
  const float* bv = (const float*)d_in[8];
  const float* Wo = (const float*)d_in[9];
  const float* bo = (const float*)d_in[10];

  const size_t NW = (size_t)EMBED * EMBED;   // 1,048,576
  const size_t NX = (size_t)MROWS * EMBED;   // 8,388,608

  if (ws_size < (4 * NW + 6 * NX) * sizeof(_Float16)) return;  // loud failure
  _Float16* ws  = (_Float16*)d_ws;
  _Float16* wqh = ws;
  _Float16* wkh = wqh + NW;
  _Float16* wvh = wkh + NW;
  _Float16* woh = wvh + NW;
  _Float16* qh  = woh + NW;
  _Float16* kh  = qh + NX;
  _Float16* vh  = kh + NX;
  _Float16* Qh  = vh + NX;
  _Float16* Kh  = Qh + NX;
  _Float16* Vph = Kh + NX;
  _Float16* Vt2 = qh;   // alias: qh dead after gemm_qkv
  _Float16* OhA = kh;   // alias: kh dead after gemm_qkv

  float* xout = (float*)d_out;
  float* attn = xout + NX;

  cast3_f32_f16<<<dim3((NX / 4 + 255) / 256, 3), dim3(256), 0, stream>>>(q, k, v, qh, kh, vh,
                                                                         (int)NX);
  cast4_f32_f16<<<dim3((NW / 4 + 255) / 256, 4), dim3(256), 0, stream>>>(
      Wq, Wk, Wv, Wo, wqh, wkh, wvh, woh, (int)NW);

  dim3 ggrid(MROWS / 128, EMBED / 128), gblk(256);
  gemm_qkv<<<dim3(MROWS / 128, EMBED / 128, 3), gblk, 0, stream>>>(qh, kh, vh, wqh, wkh, wvh,
                                                                   bq, bk, bv, Qh, Kh, Vph);

  transpose_v<<<dim3(SS / 64, BB * HEADS), dim3(256), 0, stream>>>(Vph, Vt2);

  attn_fused<<<dim3(32, 64), dim3(256), 0, stream>>>(Qh, Kh, Vt2, attn, OhA);

  gemm_out<<<ggrid, gblk, 0, stream>>>(OhA, woh, bo, xout);
}